// Round 10
// baseline (317.936 us; speedup 1.0000x reference)
//
#include <hip/hip_runtime.h>
#include <hip/hip_bf16.h>

typedef __bf16 bf16x8 __attribute__((ext_vector_type(8)));
typedef __bf16 bf16x4 __attribute__((ext_vector_type(4)));
typedef float f32x4 __attribute__((ext_vector_type(4)));

#define BN_EPS 1e-5f

// async global->LDS 16B DMA. LDS dest must be wave-uniform base + lane*16.
__device__ __forceinline__ void gl_lds16(const __bf16* g, __bf16* l) {
    __builtin_amdgcn_global_load_lds(
        (const __attribute__((address_space(1))) unsigned int*)g,
        (__attribute__((address_space(3))) unsigned int*)l,
        16, 0, 0);
}

// ---------------- P0: merged prep: wd1 permute (blocks 0-511) + small prep (blocks 512+) ----------------
__global__ __launch_bounds__(256) void prep_all_kernel(
    const float* __restrict__ wd1, __bf16* __restrict__ wd1o,
    const float* __restrict__ wd2, const float* __restrict__ w1,
    const float* __restrict__ w2,
    __bf16* __restrict__ wd2o, __bf16* __restrict__ w1o,
    __bf16* __restrict__ w2o)
{
    __shared__ float t2[64][65];
    const int tid = threadIdx.x;
    if (blockIdx.x < 512) {
        // wd1 permute+cvt: wd1o[n][q*64+oc] = (bf16)wd1[n][oc*64+q]
        const int n = blockIdx.x;
        const float* src = wd1 + (size_t)n * 4096;
        #pragma unroll
        for (int r = 0; r < 16; ++r) {
            int j = r * 256 + tid;            // j = oc*64 + q
            t2[j & 63][j >> 6] = src[j];      // t2[q][oc]
        }
        __syncthreads();
        __bf16* dst = wd1o + (size_t)n * 4096;
        #pragma unroll
        for (int r = 0; r < 16; ++r) {
            int t = r * 256 + tid;            // t = q*64 + oc
            dst[t] = (__bf16)t2[t >> 6][t & 63];
        }
        return;
    }
    int i = (blockIdx.x - 512) * 256 + tid;
    if (i < 65536) { wd2o[i] = (__bf16)wd2[i]; return; }
    i -= 65536;
    if (i < 4096) {   // w1 [oc][ic][ky][kx] -> [oc][o=(ic*5+ky)][kx pad 8], K=128
        int oc = i >> 7, rem = i & 127;
        int ot = rem >> 3, j = rem & 7;
        float v = 0.f;
        if (ot < 15 && j < 5) {
            int ic = ot / 5, ky = ot % 5;
            v = w1[((oc * 3 + ic) * 5 + ky) * 5 + j];
        }
        w1o[i] = (__bf16)v;
        return;
    }
    i -= 4096;
    if (i < 18432) {  // w2 [oc][ic][tap] -> [oc][tap][ic]
        int oc = i / 288, rem = i % 288;
        int tap = rem / 32, ic = rem % 32;
        w2o[i] = (__bf16)w2[(oc * 32 + ic) * 9 + tap];
    }
}

// ---------------- K12: fused conv1+bn+relu + conv2+bn+relu + haar+attn -> f (q-major) ----------------
// FROZEN at the verified round-8 body (112-115 µs). Restructure attempts (rounds 7/9/10)
// all regressed: conv time is invariant to occupancy, conflicts, and images/block =>
// per-block latency chain; restructuring only perturbs codegen.
__global__ __launch_bounds__(256, 5) void conv_fused_kernel(
    const float* __restrict__ x,
    const __bf16* __restrict__ w1r, const float* __restrict__ b1,
    const float* __restrict__ g1, const float* __restrict__ be1,
    const float* __restrict__ m1, const float* __restrict__ v1,
    const __bf16* __restrict__ w2r, const float* __restrict__ b2,
    const float* __restrict__ g2, const float* __restrict__ be2,
    const float* __restrict__ m2, const float* __restrict__ v2,
    const float* __restrict__ wa, const float* __restrict__ ba,
    __bf16* __restrict__ f)
{
    __shared__ __align__(16) __bf16 xsb[3 * 36 * 40];  // 8640 B: padded bf16 input
    __shared__ __align__(16) char  ubuf[23552];        // hs, later overlaid by feat/cds/atn
    __bf16* hsf  = (__bf16*)ubuf;                      // [pixel 17x17][ch stride 40] = 23120 B
    float*  feat = (float*)ubuf;                       // [64 ch][pixel stride 68] = 17408 B
    float*  cds  = (float*)(ubuf + 17408);             // [64 ch][stride 20] = 5120 B
    float*  atn  = (float*)(ubuf + 22528);             // [4][64] = 1024 B

    const int b    = blockIdx.x;
    const int tid  = threadIdx.x;
    const int lane = tid & 63;
    const int wave = tid >> 6;
    const int lo   = lane >> 4;
    const int ln   = lane & 15;

    // ---- phase 0: zero xsb + hs border ----
    {
        bf16x8 z = {};
        for (int i = tid; i < 540; i += 256) *(bf16x8*)&xsb[i * 8] = z;
        if (tid < 132) {
            int pi = tid >> 2, ch = tid & 3;
            int pix = (pi < 17) ? pi : (pi - 16) * 17;
            *(bf16x8*)&hsf[pix * 40 + ch * 8] = z;
        }
    }
    __syncthreads();

    // ---- phase 1: stage x -> xsb bf16: x[ic][iy][ix] -> xsb[ic][iy+2][ix+4] ----
    {
        const float4* xb = (const float4*)(x + (size_t)b * 3072);
        #pragma unroll
        for (int r = 0; r < 3; ++r) {
            int c = r * 256 + tid;
            int plane = c >> 8, rem = c & 255;
            int row = rem >> 3, c4 = rem & 7;
            float4 v = xb[c];
            bf16x4 h;
            h[0] = (__bf16)v.x; h[1] = (__bf16)v.y; h[2] = (__bf16)v.z; h[3] = (__bf16)v.w;
            *(bf16x4*)&xsb[plane * 1440 + (row + 2) * 40 + 4 + c4 * 4] = h;
        }
    }

    // preload conv1 weights (registers — mandatory, round-9 evidence)
    bf16x8 bw1[2][4];
    #pragma unroll
    for (int nt = 0; nt < 2; ++nt)
        #pragma unroll
        for (int s = 0; s < 4; ++s)
            bw1[nt][s] = *(const bf16x8*)(w1r + (nt * 16 + ln) * 128 + (s * 4 + lo) * 8);
    __syncthreads();

    // ---- phase 2: conv1 5x5 s2 p2 as MFMA (M=16 ox, N=32 oc, K=128) ----
    f32x4 c1[4][2] = {};
    const unsigned int* xw = (const unsigned int*)xsb;
    #pragma unroll
    for (int s = 0; s < 4; ++s) {
        const int o  = s * 4 + lo;
        const int ic = (o * 205) >> 10;
        const int ky = o - ic * 5;
        const bool dummy = (o == 15);
        const int icc = dummy ? 2 : ic;
        #pragma unroll
        for (int mt = 0; mt < 4; ++mt) {
            const int oy  = wave * 4 + mt;
            const int row = dummy ? 35 : (2 * oy + ky);   // row 35 always zero
            const int dw  = icc * 720 + row * 20 + ln + 1;
            union { unsigned int u[4]; bf16x8 v; } fa;
            fa.u[0] = xw[dw]; fa.u[1] = xw[dw + 1]; fa.u[2] = xw[dw + 2]; fa.u[3] = 0;
            #pragma unroll
            for (int nt = 0; nt < 2; ++nt)
                c1[mt][nt] = __builtin_amdgcn_mfma_f32_16x16x32_bf16(fa.v, bw1[nt][s], c1[mt][nt], 0, 0, 0);
        }
    }

    // ---- BN1 + ReLU -> hs (channel-last) ----
    #pragma unroll
    for (int nt = 0; nt < 2; ++nt) {
        const int oc  = nt * 16 + ln;
        const float inv = g1[oc] * rsqrtf(v1[oc] + BN_EPS);
        const float bb  = be1[oc] + (b1[oc] - m1[oc]) * inv;
        #pragma unroll
        for (int mt = 0; mt < 4; ++mt) {
            const int hy = wave * 4 + mt + 1;
            #pragma unroll
            for (int r = 0; r < 4; ++r) {
                const int hx = lo * 4 + r + 1;
                hsf[(hy * 17 + hx) * 40 + oc] = (__bf16)fmaxf(c1[mt][nt][r] * inv + bb, 0.f);
            }
        }
    }

    const int wm = wave >> 1, wn = wave & 1;
    bf16x8 bw2[2][9];
    #pragma unroll
    for (int nt = 0; nt < 2; ++nt) {
        const __bf16* wp = w2r + (wn * 32 + nt * 16 + ln) * 288 + lo * 8;
        #pragma unroll
        for (int ks = 0; ks < 9; ++ks)
            bw2[nt][ks] = *(const bf16x8*)(wp + ks * 32);
    }
    __syncthreads();

    // ---- phase 3: conv2 3x3 s2 p1 as MFMA (M=64 pix, N=64 oc, K=288) ----
    f32x4 c2[2][2] = {};
    {
        int pixbase[2];
        #pragma unroll
        for (int mt = 0; mt < 2; ++mt) {
            int p = wm * 32 + mt * 16 + ln;
            int qy = p >> 3, qx = p & 7;
            pixbase[mt] = (2 * qy * 17 + 2 * qx) * 40 + lo * 8;
        }
        #pragma unroll
        for (int ks = 0; ks < 9; ++ks) {
            const int ty = ks / 3, tx = ks % 3;
            bf16x8 af[2];
            #pragma unroll
            for (int mt = 0; mt < 2; ++mt)
                af[mt] = *(const bf16x8*)&hsf[pixbase[mt] + (ty * 17 + tx) * 40];
            #pragma unroll
            for (int mt = 0; mt < 2; ++mt)
                #pragma unroll
                for (int nt = 0; nt < 2; ++nt)
                    c2[mt][nt] = __builtin_amdgcn_mfma_f32_16x16x32_bf16(af[mt], bw2[nt][ks], c2[mt][nt], 0, 0, 0);
        }
    }
    __syncthreads();   // hs dead after this point; feat overlays it

    // ---- BN2 + ReLU -> feat[oc][pixel stride 68]; f32x4 writes at bank-quad floor ----
    #pragma unroll
    for (int nt = 0; nt < 2; ++nt) {
        const int oc  = wn * 32 + nt * 16 + ln;
        const float inv = g2[oc] * rsqrtf(v2[oc] + BN_EPS);
        const float bb  = be2[oc] + (b2[oc] - m2[oc]) * inv;
        #pragma unroll
        for (int mt = 0; mt < 2; ++mt) {
            const int p0 = wm * 32 + mt * 16 + lo * 4;
            f32x4 o;
            #pragma unroll
            for (int r = 0; r < 4; ++r)
                o[r] = fmaxf(c2[mt][nt][r] * inv + bb, 0.f);
            *(f32x4*)&feat[oc * 68 + p0] = o;
        }
    }
    __syncthreads();

    // ---- phase 4: Haar cD via 4x ds_read_b128 per thread (conflict-free at b128 floor) ----
    {
        const int c = tid >> 2, y = tid & 3;
        const float* fr = feat + c * 68 + 16 * y;
        f32x4 t0 = *(const f32x4*)(fr);        // row 2y,   px 0-3
        f32x4 t2v = *(const f32x4*)(fr + 4);   // row 2y,   px 4-7
        f32x4 t1 = *(const f32x4*)(fr + 8);    // row 2y+1, px 0-3
        f32x4 t3 = *(const f32x4*)(fr + 12);   // row 2y+1, px 4-7
        f32x4 o;
        o[0] = 0.5f * (t0[0] - t0[1] - t1[0] + t1[1]);
        o[1] = 0.5f * (t0[2] - t0[3] - t1[2] + t1[3]);
        o[2] = 0.5f * (t2v[0] - t2v[1] - t3[0] + t3[1]);
        o[3] = 0.5f * (t2v[2] - t2v[3] - t3[2] + t3[3]);
        *(f32x4*)&cds[c * 20 + y * 4] = o;
    }
    __syncthreads();

    // ---- phase 5: gating + attention (feat reads lane-consecutive -> conflict-free) ----
    const int q  = tid & 63;
    const int g  = wave;
    const int qy2 = q >> 3, qx2 = q & 7;
    const int qq = (qy2 >> 1) * 4 + (qx2 >> 1);
    float a2[16];
    float part = 0.f;
    #pragma unroll
    for (int j = 0; j < 16; ++j) {
        int oc = g * 16 + j;
        float v = feat[oc * 68 + q] * cds[oc * 20 + qq];
        a2[j] = v;
        part += v * wa[oc];
    }
    atn[g * 64 + q] = part;
    __syncthreads();
    float s2  = atn[q] + atn[64 + q] + atn[128 + q] + atn[192 + q] + ba[0];
    float sig = 1.f / (1.f + __expf(-s2));

    // ---- write f q-major: f[b][q*64 + oc], 2 x b128 per lane ----
    bf16x8 fo0, fo1;
    #pragma unroll
    for (int j = 0; j < 8; ++j) {
        fo0[j] = (__bf16)(a2[j] * sig);
        fo1[j] = (__bf16)(a2[j + 8] * sig);
    }
    __bf16* fb = f + (size_t)b * 4096 + q * 64 + g * 16;
    *(bf16x8*)fb = fo0;
    *(bf16x8*)(fb + 8) = fo1;
}

// ---------------- K3a: dense1 split-K GEMM with COUNTED-VMCNT pipeline ----------------
// round-16: T4 recipe. Round-5's dbuf failed because __syncthreads drains vmcnt(0);
// here raw s_barrier + s_waitcnt vmcnt(6) keeps the next tile's 6 loads/thread in
// flight ACROSS the barrier (m218: counted-vs-drain0 = +38-73%). Per K-step:
//   issue 6 gl_lds16 -> buf[nxt]; vmcnt(6) (tile-k done, 6 newest in flight);
//   s_barrier; MFMA from buf[cur]; lgkmcnt(0); s_barrier (safe to overwrite).
// sched_barrier(0) after each asm wait (rule #18). LDS 48 KB -> 3 blocks/CU.
__global__ __launch_bounds__(256, 3) void gemm1_split_kernel(
    const __bf16* __restrict__ A, const __bf16* __restrict__ B,
    float* __restrict__ P)
{
    const int K = 4096, NOUT = 512, KH = 2048;
    __shared__ __align__(16) __bf16 As[2][64][64];
    __shared__ __align__(16) __bf16 Bs[2][128][64];
    const int tid  = threadIdx.x;
    const int lane = tid & 63;
    const int wave = tid >> 6;
    const int lo = lane >> 4, ln = lane & 15;
    const int bid = blockIdx.x;
    const int swz = (bid & 7) * 128 + (bid >> 3);   // bijective: 1024 % 8 == 0
    const int n0  = (swz & 3) * 128;                // n fastest: A-panel sharers co-XCD
    const int zz  = (swz >> 2) & 1;
    const int m0  = (swz >> 3) * 64;
    const int ks0 = zz * KH;
    const int sw  = ln & 7;

    f32x4 acc[4][2] = {};

    auto STAGE = [&](int k0, int bb) {
        #pragma unroll
        for (int r = 0; r < 2; ++r) {
            int i = r * 256 + tid;
            int row = i >> 3, cs = i & 7;
            gl_lds16(A + (size_t)(m0 + row) * K + k0 + (cs ^ (row & 7)) * 8, &As[bb][0][0] + i * 8);
        }
        #pragma unroll
        for (int r = 0; r < 4; ++r) {
            int i = r * 256 + tid;
            int row = i >> 3, cs = i & 7;
            gl_lds16(B + (size_t)(n0 + row) * K + k0 + (cs ^ (row & 7)) * 8, &Bs[bb][0][0] + i * 8);
        }
    };
    auto COMPUTE = [&](int bb) {
        #pragma unroll
        for (int s = 0; s < 2; ++s) {
            const int c = s * 4 + lo;
            const int slot = (c ^ sw) * 8;
            bf16x8 af[4], bfr[2];
            #pragma unroll
            for (int mt = 0; mt < 4; ++mt)
                af[mt] = *(const bf16x8*)(&As[bb][mt * 16 + ln][slot]);
            #pragma unroll
            for (int nt = 0; nt < 2; ++nt)
                bfr[nt] = *(const bf16x8*)(&Bs[bb][wave * 32 + nt * 16 + ln][slot]);
            #pragma unroll
            for (int mt = 0; mt < 4; ++mt)
                #pragma unroll
                for (int nt = 0; nt < 2; ++nt)
                    acc[mt][nt] = __builtin_amdgcn_mfma_f32_16x16x32_bf16(af[mt], bfr[nt], acc[mt][nt], 0, 0, 0);
        }
    };

    STAGE(ks0, 0);                                   // prologue: tile 0 in flight (6 loads)
    for (int t = 0; t < 31; ++t) {
        STAGE(ks0 + (t + 1) * 64, (t + 1) & 1);      // 6 more loads -> 12 outstanding
        asm volatile("s_waitcnt vmcnt(6)" ::: "memory");   // tile t complete; t+1 in flight
        __builtin_amdgcn_sched_barrier(0);
        __builtin_amdgcn_s_barrier();                // all waves' tile-t slices in LDS
        COMPUTE(t & 1);
        asm volatile("s_waitcnt lgkmcnt(0)" ::: "memory"); // my ds_reads retired
        __builtin_amdgcn_sched_barrier(0);
        __builtin_amdgcn_s_barrier();                // everyone done reading buf[t&1]
    }
    asm volatile("s_waitcnt vmcnt(0)" ::: "memory"); // last tile complete
    __builtin_amdgcn_sched_barrier(0);
    __builtin_amdgcn_s_barrier();
    COMPUTE(1);                                      // t = 31 -> buf 1

    float* Pp = P + (size_t)zz * 8192 * 512;
    #pragma unroll
    for (int mt = 0; mt < 4; ++mt)
        #pragma unroll
        for (int nt = 0; nt < 2; ++nt)
            #pragma unroll
            for (int r = 0; r < 4; ++r) {
                int m = m0 + mt * 16 + lo * 4 + r;
                int n = n0 + wave * 32 + nt * 16 + ln;
                Pp[(size_t)m * NOUT + n] = acc[mt][nt][r];
            }
}

// ---------------- K3-fallback: single-pass gemm1 (XCD swizzle, 512 blocks 1D) ----------------
__global__ __launch_bounds__(256) void gemm1_kernel(
    const __bf16* __restrict__ A, const __bf16* __restrict__ B,
    const float* __restrict__ bias, __bf16* __restrict__ C)
{
    const int K = 4096, NOUT = 512;
    __shared__ __align__(16) __bf16 As[64][64];
    __shared__ __align__(16) __bf16 Bs[128][64];
    const int tid  = threadIdx.x;
    const int lane = tid & 63;
    const int wave = tid >> 6;
    const int lo = lane >> 4, ln = lane & 15;
    const int bid = blockIdx.x;
    const int swz = (bid & 7) * 64 + (bid >> 3);
    const int n0  = (swz & 3) * 128;
    const int m0  = (swz >> 2) * 64;
    const int sw = ln & 7;
    f32x4 acc[4][2] = {};
    for (int k0 = 0; k0 < K; k0 += 64) {
        #pragma unroll
        for (int r = 0; r < 2; ++r) {
            int i = r * 256 + tid;
            int row = i >> 3, cs = i & 7;
            gl_lds16(A + (size_t)(m0 + row) * K + k0 + (cs ^ (row & 7)) * 8, &As[0][0] + i * 8);
        }
        #pragma unroll
        for (int r = 0; r < 4; ++r) {
            int i = r * 256 + tid;
            int row = i >> 3, cs = i & 7;
            gl_lds16(B + (size_t)(n0 + row) * K + k0 + (cs ^ (row & 7)) * 8, &Bs[0][0] + i * 8);
        }
        __syncthreads();
        #pragma unroll
        for (int s = 0; s < 2; ++s) {
            const int c = s * 4 + lo;
            const int slot = (c ^ sw) * 8;
            bf16x8 af[4], bfr[2];
            #pragma unroll
            for (int mt = 0; mt < 4; ++mt)
                af[mt] = *(const bf16x8*)(&As[mt * 16 + ln][slot]);
            #pragma unroll
            for (int nt = 0; nt < 2; ++nt)
                bfr[nt] = *(const bf16x8*)(&Bs[wave * 32 + nt * 16 + ln][slot]);
            #pragma unroll
            for (int mt = 0; mt < 4; ++mt)
                #pragma unroll
                for (int nt = 0; nt < 2; ++nt)
                    acc[mt][nt] = __builtin_amdgcn_mfma_f32_16x16x32_bf16(af[mt], bfr[nt], acc[mt][nt], 0, 0, 0);
        }
        __syncthreads();
    }
    #pragma unroll
    for (int mt = 0; mt < 4; ++mt)
        #pragma unroll
        for (int nt = 0; nt < 2; ++nt)
            #pragma unroll
            for (int r = 0; r < 4; ++r) {
                int m = m0 + mt * 16 + lo * 4 + r;
                int n = n0 + wave * 32 + nt * 16 + ln;
                float v = acc[mt][nt][r] + bias[n];
                C[(size_t)m * NOUT + n] = (__bf16)fmaxf(v, 0.f);
            }
}

// ---------------- K4: dense2 (+fused reduce1): out = sigmoid(relu(P0+P1+bd1) @ B^T + bd2) ----------------
__global__ __launch_bounds__(256, 4) void gemm2_kernel(
    const __bf16* __restrict__ A, const float* __restrict__ P,
    const float* __restrict__ bd1, const __bf16* __restrict__ B,
    const float* __restrict__ bias, float* __restrict__ Out, int fused)
{
    const int K = 512, NOUT = 128;
    __shared__ __align__(16) __bf16 As[32][64];
    __shared__ __align__(16) __bf16 Bs[128][64];
    const int tid  = threadIdx.x;
    const int lane = tid & 63;
    const int wave = tid >> 6;
    const int lo = lane >> 4, ln = lane & 15;
    const int m0 = blockIdx.x * 32;
    const int sw = ln & 7;
    const size_t HALF = (size_t)8192 * 512;
    f32x4 acc[2][2] = {};
    for (int k0 = 0; k0 < K; k0 += 64) {
        {
            int i = tid;                       // 32 rows x 8 chunks = 256
            int row = i >> 3, cs = i & 7;
            int k = k0 + (cs ^ (row & 7)) * 8;
            if (fused) {
                const float* p0 = P + (size_t)(m0 + row) * K + k;
                f32x4 a0 = *(const f32x4*)(p0);
                f32x4 a1 = *(const f32x4*)(p0 + 4);
                f32x4 c0 = *(const f32x4*)(p0 + HALF);
                f32x4 c1 = *(const f32x4*)(p0 + HALF + 4);
                f32x4 b0 = *(const f32x4*)(bd1 + k);
                f32x4 b1v = *(const f32x4*)(bd1 + k + 4);
                bf16x8 o;
                #pragma unroll
                for (int j = 0; j < 4; ++j) {
                    o[j]     = (__bf16)fmaxf(a0[j] + c0[j] + b0[j], 0.f);
                    o[j + 4] = (__bf16)fmaxf(a1[j] + c1[j] + b1v[j], 0.f);
                }
                *(bf16x8*)(&As[0][0] + i * 8) = o;
            } else {
                gl_lds16(A + (size_t)(m0 + row) * K + k, &As[0][0] + i * 8);
            }
        }
        #pragma unroll
        for (int r = 0; r < 4; ++r) {
            int i = r * 256 + tid;
            int row = i >> 3, cs = i & 7;
            gl_lds16(B + (size_t)row * K + k0 + (cs ^ (row & 7)) * 8, &Bs[0][0] + i * 8);
        }
        __syncthreads();
        #pragma unroll
        for (int s = 0; s < 2; ++s) {
            const int c = s * 4 + lo;
            const int slot = (c ^ sw) * 8;
            bf16x8 af[2], bfr[2];
            #pragma unroll
            for (int mt = 0; mt < 2; ++mt)
                af[mt] = *(const bf16x8*)(&As[mt * 16 + ln][slot]);
            #pragma unroll
            for (int nt = 0; nt < 2; ++nt)
                bfr[nt] = *(const bf16x8*)(&Bs[wave * 32 + nt * 16 + ln][slot]);
            #pragma unroll
            for (int mt = 0; mt < 2; ++mt)
                #pragma unroll
                for (int nt = 0; nt < 2; ++nt)
                    acc[mt][nt] = __builtin_amdgcn_mfma_f32_16x16x32_bf16(af[mt], bfr[nt], acc[mt][nt], 0, 0, 0);
        }
        __syncthreads();
    }
    #pragma unroll
    for (int mt = 0; mt < 2; ++mt)
        #pragma unroll
        for (int nt = 0; nt < 2; ++nt)
            #pragma unroll
            for (int r = 0; r < 4; ++r) {
                int m = m0 + mt * 16 + lo * 4 + r;
                int n = wave * 32 + nt * 16 + ln;
                float v = acc[mt][nt][r] + bias[n];
                Out[(size_t)m * NOUT + n] = 1.f / (1.f + __expf(-v));
            }
}

extern "C" void kernel_launch(void* const* d_in, const int* in_sizes, int n_in,
                              void* d_out, int out_size, void* d_ws, size_t ws_size,
                              hipStream_t stream)
{
    const float* x   = (const float*)d_in[0];
    const float* w1  = (const float*)d_in[1];
    const float* b1  = (const float*)d_in[2];
    const float* g1  = (const float*)d_in[3];
    const float* be1 = (const float*)d_in[4];
    const float* m1  = (const float*)d_in[5];
    const float* v1  = (const float*)d_in[6];
    const float* w2  = (const float*)d_in[7];
    const float* b2  = (const float*)d_in[8];
    const float* g2  = (const float*)d_in[9];
    const float* be2 = (const float*)d_in[10];
    const float* m2  = (const float*)d_in[11];
    const float* v2  = (const float*)d_in[12];
    const float* wa  = (const float*)d_in[13];
    const float* ba  = (const float*)d_in[14];
    const float* wd1 = (const float*)d_in[15];
    const float* bd1 = (const float*)d_in[16];
    const float* wd2 = (const float*)d_in[17];
    const float* bd2 = (const float*)d_in[18];

    char* ws = (char*)d_ws;
    const size_t SZ_F  = 67108864;          // f: 64 MiB
    const size_t SZ_P  = 33554432;          // partials: 2 x 16 MiB
    const size_t SZ_H1 = 8388608;           // h1: 8 MiB (fallback only, slot reserved)
    const bool use_split = ws_size >= (SZ_F + SZ_P + SZ_H1 + 4194304 + 131072 + 65536 + 8192);

    __bf16* f_bf = (__bf16*)ws;
    float*  P;
    __bf16* h1_bf;
    char* tail;
    if (use_split) {
        P      = (float*)(ws + SZ_F);
        h1_bf  = (__bf16*)(ws + SZ_F + SZ_P);
        tail   = ws + SZ_F + SZ_P + SZ_H1;
    } else {
        P      = nullptr;
        h1_bf  = (__bf16*)(ws + SZ_F);
        tail   = ws + SZ_F + SZ_H1;
    }
    __bf16* wd1_bf = (__bf16*)tail;                       // 4 MiB (permuted)
    __bf16* wd2_bf = (__bf16*)(tail + 4194304);           // 128 KiB
    __bf16* w2r_bf = (__bf16*)(tail + 4194304 + 131072);  // 64 KiB slot
    __bf16* w1r_bf = (__bf16*)(tail + 4194304 + 131072 + 65536); // 8 KiB

    // one merged prep dispatch: blocks 0-511 = wd1 permute, 512-855 = small prep
    prep_all_kernel<<<856, 256, 0, stream>>>(wd1, wd1_bf, wd2, w1, w2, wd2_bf, w1r_bf, w2r_bf);

    conv_fused_kernel<<<8192, 256, 0, stream>>>(x, w1r_bf, b1, g1, be1, m1, v1,
                                                w2r_bf, b2, g2, be2, m2, v2, wa, ba, f_bf);

    if (use_split) {
        gemm1_split_kernel<<<1024, 256, 0, stream>>>(f_bf, wd1_bf, P);
        gemm2_kernel<<<256, 256, 0, stream>>>(nullptr, P, bd1, wd2_bf, bd2, (float*)d_out, 1);
    } else {
        gemm1_kernel<<<512, 256, 0, stream>>>(f_bf, wd1_bf, bd1, h1_bf);
        gemm2_kernel<<<256, 256, 0, stream>>>(h1_bf, nullptr, bd1, wd2_bf, bd2, (float*)d_out, 0);
    }
}

// Round 11
// 294.965 us; speedup vs baseline: 1.0779x; 1.0779x over previous
//
#include <hip/hip_runtime.h>
#include <hip/hip_bf16.h>

typedef __bf16 bf16x8 __attribute__((ext_vector_type(8)));
typedef __bf16 bf16x4 __attribute__((ext_vector_type(4)));
typedef float f32x4 __attribute__((ext_vector_type(4)));

#define BN_EPS 1e-5f

// async global->LDS 16B DMA. LDS dest must be wave-uniform base + lane*16.
__device__ __forceinline__ void gl_lds16(const __bf16* g, __bf16* l) {
    __builtin_amdgcn_global_load_lds(
        (const __attribute__((address_space(1))) unsigned int*)g,
        (__attribute__((address_space(3))) unsigned int*)l,
        16, 0, 0);
}

// ---------------- P0: merged prep: wd1 permute (blocks 0-511) + small prep (blocks 512+) ----------------
__global__ __launch_bounds__(256) void prep_all_kernel(
    const float* __restrict__ wd1, __bf16* __restrict__ wd1o,
    const float* __restrict__ wd2, const float* __restrict__ w1,
    const float* __restrict__ w2,
    __bf16* __restrict__ wd2o, __bf16* __restrict__ w1o,
    __bf16* __restrict__ w2o)
{
    __shared__ float t2[64][65];
    const int tid = threadIdx.x;
    if (blockIdx.x < 512) {
        // wd1 permute+cvt: wd1o[n][q*64+oc] = (bf16)wd1[n][oc*64+q]
        const int n = blockIdx.x;
        const float* src = wd1 + (size_t)n * 4096;
        #pragma unroll
        for (int r = 0; r < 16; ++r) {
            int j = r * 256 + tid;            // j = oc*64 + q
            t2[j & 63][j >> 6] = src[j];      // t2[q][oc]
        }
        __syncthreads();
        __bf16* dst = wd1o + (size_t)n * 4096;
        #pragma unroll
        for (int r = 0; r < 16; ++r) {
            int t = r * 256 + tid;            // t = q*64 + oc
            dst[t] = (__bf16)t2[t >> 6][t & 63];
        }
        return;
    }
    int i = (blockIdx.x - 512) * 256 + tid;
    if (i < 65536) { wd2o[i] = (__bf16)wd2[i]; return; }
    i -= 65536;
    if (i < 4096) {   // w1 [oc][ic][ky][kx] -> [oc][o=(ic*5+ky)][kx pad 8], K=128
        int oc = i >> 7, rem = i & 127;
        int ot = rem >> 3, j = rem & 7;
        float v = 0.f;
        if (ot < 15 && j < 5) {
            int ic = ot / 5, ky = ot % 5;
            v = w1[((oc * 3 + ic) * 5 + ky) * 5 + j];
        }
        w1o[i] = (__bf16)v;
        return;
    }
    i -= 4096;
    if (i < 18432) {  // w2 [oc][ic][tap] -> [oc][tap][ic]
        int oc = i / 288, rem = i % 288;
        int tap = rem / 32, ic = rem % 32;
        w2o[i] = (__bf16)w2[(oc * 32 + ic) * 9 + tap];
    }
}

// ---------------- K12: fused conv1+bn+relu + conv2+bn+relu + haar+attn -> f (q-major) ----------------
// FROZEN at the verified round-8 body (112-115 µs). Restructure attempts (rounds 7/9/10)
// all regressed: conv time is invariant to occupancy, conflicts, and images/block =>
// per-block latency chain; restructuring only perturbs codegen.
__global__ __launch_bounds__(256, 5) void conv_fused_kernel(
    const float* __restrict__ x,
    const __bf16* __restrict__ w1r, const float* __restrict__ b1,
    const float* __restrict__ g1, const float* __restrict__ be1,
    const float* __restrict__ m1, const float* __restrict__ v1,
    const __bf16* __restrict__ w2r, const float* __restrict__ b2,
    const float* __restrict__ g2, const float* __restrict__ be2,
    const float* __restrict__ m2, const float* __restrict__ v2,
    const float* __restrict__ wa, const float* __restrict__ ba,
    __bf16* __restrict__ f)
{
    __shared__ __align__(16) __bf16 xsb[3 * 36 * 40];  // 8640 B: padded bf16 input
    __shared__ __align__(16) char  ubuf[23552];        // hs, later overlaid by feat/cds/atn
    __bf16* hsf  = (__bf16*)ubuf;                      // [pixel 17x17][ch stride 40] = 23120 B
    float*  feat = (float*)ubuf;                       // [64 ch][pixel stride 68] = 17408 B
    float*  cds  = (float*)(ubuf + 17408);             // [64 ch][stride 20] = 5120 B
    float*  atn  = (float*)(ubuf + 22528);             // [4][64] = 1024 B

    const int b    = blockIdx.x;
    const int tid  = threadIdx.x;
    const int lane = tid & 63;
    const int wave = tid >> 6;
    const int lo   = lane >> 4;
    const int ln   = lane & 15;

    // ---- phase 0: zero xsb + hs border ----
    {
        bf16x8 z = {};
        for (int i = tid; i < 540; i += 256) *(bf16x8*)&xsb[i * 8] = z;
        if (tid < 132) {
            int pi = tid >> 2, ch = tid & 3;
            int pix = (pi < 17) ? pi : (pi - 16) * 17;
            *(bf16x8*)&hsf[pix * 40 + ch * 8] = z;
        }
    }
    __syncthreads();

    // ---- phase 1: stage x -> xsb bf16: x[ic][iy][ix] -> xsb[ic][iy+2][ix+4] ----
    {
        const float4* xb = (const float4*)(x + (size_t)b * 3072);
        #pragma unroll
        for (int r = 0; r < 3; ++r) {
            int c = r * 256 + tid;
            int plane = c >> 8, rem = c & 255;
            int row = rem >> 3, c4 = rem & 7;
            float4 v = xb[c];
            bf16x4 h;
            h[0] = (__bf16)v.x; h[1] = (__bf16)v.y; h[2] = (__bf16)v.z; h[3] = (__bf16)v.w;
            *(bf16x4*)&xsb[plane * 1440 + (row + 2) * 40 + 4 + c4 * 4] = h;
        }
    }

    // preload conv1 weights (registers — mandatory, round-9 evidence)
    bf16x8 bw1[2][4];
    #pragma unroll
    for (int nt = 0; nt < 2; ++nt)
        #pragma unroll
        for (int s = 0; s < 4; ++s)
            bw1[nt][s] = *(const bf16x8*)(w1r + (nt * 16 + ln) * 128 + (s * 4 + lo) * 8);
    __syncthreads();

    // ---- phase 2: conv1 5x5 s2 p2 as MFMA (M=16 ox, N=32 oc, K=128) ----
    f32x4 c1[4][2] = {};
    const unsigned int* xw = (const unsigned int*)xsb;
    #pragma unroll
    for (int s = 0; s < 4; ++s) {
        const int o  = s * 4 + lo;
        const int ic = (o * 205) >> 10;
        const int ky = o - ic * 5;
        const bool dummy = (o == 15);
        const int icc = dummy ? 2 : ic;
        #pragma unroll
        for (int mt = 0; mt < 4; ++mt) {
            const int oy  = wave * 4 + mt;
            const int row = dummy ? 35 : (2 * oy + ky);   // row 35 always zero
            const int dw  = icc * 720 + row * 20 + ln + 1;
            union { unsigned int u[4]; bf16x8 v; } fa;
            fa.u[0] = xw[dw]; fa.u[1] = xw[dw + 1]; fa.u[2] = xw[dw + 2]; fa.u[3] = 0;
            #pragma unroll
            for (int nt = 0; nt < 2; ++nt)
                c1[mt][nt] = __builtin_amdgcn_mfma_f32_16x16x32_bf16(fa.v, bw1[nt][s], c1[mt][nt], 0, 0, 0);
        }
    }

    // ---- BN1 + ReLU -> hs (channel-last) ----
    #pragma unroll
    for (int nt = 0; nt < 2; ++nt) {
        const int oc  = nt * 16 + ln;
        const float inv = g1[oc] * rsqrtf(v1[oc] + BN_EPS);
        const float bb  = be1[oc] + (b1[oc] - m1[oc]) * inv;
        #pragma unroll
        for (int mt = 0; mt < 4; ++mt) {
            const int hy = wave * 4 + mt + 1;
            #pragma unroll
            for (int r = 0; r < 4; ++r) {
                const int hx = lo * 4 + r + 1;
                hsf[(hy * 17 + hx) * 40 + oc] = (__bf16)fmaxf(c1[mt][nt][r] * inv + bb, 0.f);
            }
        }
    }

    const int wm = wave >> 1, wn = wave & 1;
    bf16x8 bw2[2][9];
    #pragma unroll
    for (int nt = 0; nt < 2; ++nt) {
        const __bf16* wp = w2r + (wn * 32 + nt * 16 + ln) * 288 + lo * 8;
        #pragma unroll
        for (int ks = 0; ks < 9; ++ks)
            bw2[nt][ks] = *(const bf16x8*)(wp + ks * 32);
    }
    __syncthreads();

    // ---- phase 3: conv2 3x3 s2 p1 as MFMA (M=64 pix, N=64 oc, K=288) ----
    f32x4 c2[2][2] = {};
    {
        int pixbase[2];
        #pragma unroll
        for (int mt = 0; mt < 2; ++mt) {
            int p = wm * 32 + mt * 16 + ln;
            int qy = p >> 3, qx = p & 7;
            pixbase[mt] = (2 * qy * 17 + 2 * qx) * 40 + lo * 8;
        }
        #pragma unroll
        for (int ks = 0; ks < 9; ++ks) {
            const int ty = ks / 3, tx = ks % 3;
            bf16x8 af[2];
            #pragma unroll
            for (int mt = 0; mt < 2; ++mt)
                af[mt] = *(const bf16x8*)&hsf[pixbase[mt] + (ty * 17 + tx) * 40];
            #pragma unroll
            for (int mt = 0; mt < 2; ++mt)
                #pragma unroll
                for (int nt = 0; nt < 2; ++nt)
                    c2[mt][nt] = __builtin_amdgcn_mfma_f32_16x16x32_bf16(af[mt], bw2[nt][ks], c2[mt][nt], 0, 0, 0);
        }
    }
    __syncthreads();   // hs dead after this point; feat overlays it

    // ---- BN2 + ReLU -> feat[oc][pixel stride 68]; f32x4 writes at bank-quad floor ----
    #pragma unroll
    for (int nt = 0; nt < 2; ++nt) {
        const int oc  = wn * 32 + nt * 16 + ln;
        const float inv = g2[oc] * rsqrtf(v2[oc] + BN_EPS);
        const float bb  = be2[oc] + (b2[oc] - m2[oc]) * inv;
        #pragma unroll
        for (int mt = 0; mt < 2; ++mt) {
            const int p0 = wm * 32 + mt * 16 + lo * 4;
            f32x4 o;
            #pragma unroll
            for (int r = 0; r < 4; ++r)
                o[r] = fmaxf(c2[mt][nt][r] * inv + bb, 0.f);
            *(f32x4*)&feat[oc * 68 + p0] = o;
        }
    }
    __syncthreads();

    // ---- phase 4: Haar cD via 4x ds_read_b128 per thread (conflict-free at b128 floor) ----
    {
        const int c = tid >> 2, y = tid & 3;
        const float* fr = feat + c * 68 + 16 * y;
        f32x4 t0 = *(const f32x4*)(fr);        // row 2y,   px 0-3
        f32x4 t2v = *(const f32x4*)(fr + 4);   // row 2y,   px 4-7
        f32x4 t1 = *(const f32x4*)(fr + 8);    // row 2y+1, px 0-3
        f32x4 t3 = *(const f32x4*)(fr + 12);   // row 2y+1, px 4-7
        f32x4 o;
        o[0] = 0.5f * (t0[0] - t0[1] - t1[0] + t1[1]);
        o[1] = 0.5f * (t0[2] - t0[3] - t1[2] + t1[3]);
        o[2] = 0.5f * (t2v[0] - t2v[1] - t3[0] + t3[1]);
        o[3] = 0.5f * (t2v[2] - t2v[3] - t3[2] + t3[3]);
        *(f32x4*)&cds[c * 20 + y * 4] = o;
    }
    __syncthreads();

    // ---- phase 5: gating + attention (feat reads lane-consecutive -> conflict-free) ----
    const int q  = tid & 63;
    const int g  = wave;
    const int qy2 = q >> 3, qx2 = q & 7;
    const int qq = (qy2 >> 1) * 4 + (qx2 >> 1);
    float a2[16];
    float part = 0.f;
    #pragma unroll
    for (int j = 0; j < 16; ++j) {
        int oc = g * 16 + j;
        float v = feat[oc * 68 + q] * cds[oc * 20 + qq];
        a2[j] = v;
        part += v * wa[oc];
    }
    atn[g * 64 + q] = part;
    __syncthreads();
    float s2  = atn[q] + atn[64 + q] + atn[128 + q] + atn[192 + q] + ba[0];
    float sig = 1.f / (1.f + __expf(-s2));

    // ---- write f q-major: f[b][q*64 + oc], 2 x b128 per lane ----
    bf16x8 fo0, fo1;
    #pragma unroll
    for (int j = 0; j < 8; ++j) {
        fo0[j] = (__bf16)(a2[j] * sig);
        fo1[j] = (__bf16)(a2[j + 8] * sig);
    }
    __bf16* fb = f + (size_t)b * 4096 + q * 64 + g * 16;
    *(bf16x8*)fb = fo0;
    *(bf16x8*)(fb + 8) = fo1;
}

// ---------------- K3: dense1 with IN-BLOCK split-K: h1 = relu(f @ wd1p^T + bd1) -> bf16 ----------------
// Best measured config (round-8, 298.0 total). 512 threads = 2 K-groups x 4 waves. Each
// group runs the round-6 64x128 wave-level loop over its K-half (KH=2048, 32 steps);
// groups reduce via a one-time LDS epilogue. No global P round-trip.
// LDS: staging 48 KB, epilogue overlays it with Ps[64][132] f32 (33.8 KB).
__global__ __launch_bounds__(512, 4) void gemm1_ib_kernel(
    const __bf16* __restrict__ A, const __bf16* __restrict__ B,
    const float* __restrict__ bias, __bf16* __restrict__ C)
{
    const int K = 4096, NOUT = 512, KH = 2048;
    __shared__ __align__(16) char lds[49152];          // 48 KB
    const int tid  = threadIdx.x;
    const int grp  = tid >> 8;           // K-group 0/1
    const int lt   = tid & 255;          // thread within group (round-6 tid)
    const int lane = lt & 63;
    const int wv   = lt >> 6;            // wave within group [0,4)
    const int lo   = lane >> 4, ln = lane & 15;
    __bf16* Asg = (__bf16*)lds + grp * 4096;           // [64][64] per group
    __bf16* Bsg = (__bf16*)(lds + 16384) + grp * 8192; // [128][64] per group

    const int bid = blockIdx.x;
    const int swz = (bid & 7) * 64 + (bid >> 3);       // bijective: 512 % 8 == 0
    const int n0  = (swz & 3) * 128;                   // n fastest: A-panel sharers co-XCD
    const int m0  = (swz >> 2) * 64;
    const int kb  = grp * KH;
    const int sw  = ln & 7;

    f32x4 acc[4][2] = {};
    for (int k0 = 0; k0 < KH; k0 += 64) {
        const int kk = kb + k0;
        #pragma unroll
        for (int r = 0; r < 2; ++r) {
            int i = r * 256 + lt;
            int row = i >> 3, cs = i & 7;
            gl_lds16(A + (size_t)(m0 + row) * K + kk + (cs ^ (row & 7)) * 8, Asg + i * 8);
        }
        #pragma unroll
        for (int r = 0; r < 4; ++r) {
            int i = r * 256 + lt;
            int row = i >> 3, cs = i & 7;
            gl_lds16(B + (size_t)(n0 + row) * K + kk + (cs ^ (row & 7)) * 8, Bsg + i * 8);
        }
        __syncthreads();
        #pragma unroll
        for (int s = 0; s < 2; ++s) {
            const int c = s * 4 + lo;
            const int slot = (c ^ sw) * 8;
            bf16x8 af[4], bfr[2];
            #pragma unroll
            for (int mt = 0; mt < 4; ++mt)
                af[mt] = *(const bf16x8*)(Asg + (mt * 16 + ln) * 64 + slot);
            #pragma unroll
            for (int nt = 0; nt < 2; ++nt)
                bfr[nt] = *(const bf16x8*)(Bsg + (wv * 32 + nt * 16 + ln) * 64 + slot);
            #pragma unroll
            for (int mt = 0; mt < 4; ++mt)
                #pragma unroll
                for (int nt = 0; nt < 2; ++nt)
                    acc[mt][nt] = __builtin_amdgcn_mfma_f32_16x16x32_bf16(af[mt], bfr[nt], acc[mt][nt], 0, 0, 0);
        }
        __syncthreads();
    }

    // epilogue: group 1 parks partials in LDS (stride 132 : 2-way max = free), group 0 reduces.
    float* Ps = (float*)lds;                           // [64][132] = 33792 B
    if (grp == 1) {
        #pragma unroll
        for (int mt = 0; mt < 4; ++mt)
            #pragma unroll
            for (int nt = 0; nt < 2; ++nt)
                #pragma unroll
                for (int r = 0; r < 4; ++r)
                    Ps[(mt * 16 + lo * 4 + r) * 132 + wv * 32 + nt * 16 + ln] = acc[mt][nt][r];
    }
    __syncthreads();
    if (grp == 0) {
        #pragma unroll
        for (int mt = 0; mt < 4; ++mt)
            #pragma unroll
            for (int nt = 0; nt < 2; ++nt)
                #pragma unroll
                for (int r = 0; r < 4; ++r) {
                    const int ml = mt * 16 + lo * 4 + r;
                    const int nl = wv * 32 + nt * 16 + ln;
                    float v = acc[mt][nt][r] + Ps[ml * 132 + nl] + bias[n0 + nl];
                    C[(size_t)(m0 + ml) * NOUT + n0 + nl] = (__bf16)fmaxf(v, 0.f);
                }
    }
}

// ---------------- K4: dense2: out[8192,128] = sigmoid(h1 @ wd2^T + bd2) ----------------
// validated rounds 0-3 path (reads bf16 h1 via gl_lds16).
__global__ __launch_bounds__(256, 4) void gemm2_kernel(
    const __bf16* __restrict__ A, const __bf16* __restrict__ B,
    const float* __restrict__ bias, float* __restrict__ Out)
{
    const int K = 512, NOUT = 128;
    __shared__ __align__(16) __bf16 As[32][64];
    __shared__ __align__(16) __bf16 Bs[128][64];
    const int tid  = threadIdx.x;
    const int lane = tid & 63;
    const int wave = tid >> 6;
    const int lo = lane >> 4, ln = lane & 15;
    const int m0 = blockIdx.x * 32;
    const int sw = ln & 7;
    f32x4 acc[2][2] = {};
    for (int k0 = 0; k0 < K; k0 += 64) {
        {
            int i = tid;                       // 32 rows x 8 chunks = 256
            int row = i >> 3, cs = i & 7;
            gl_lds16(A + (size_t)(m0 + row) * K + k0 + (cs ^ (row & 7)) * 8, &As[0][0] + i * 8);
        }
        #pragma unroll
        for (int r = 0; r < 4; ++r) {
            int i = r * 256 + tid;
            int row = i >> 3, cs = i & 7;
            gl_lds16(B + (size_t)row * K + k0 + (cs ^ (row & 7)) * 8, &Bs[0][0] + i * 8);
        }
        __syncthreads();
        #pragma unroll
        for (int s = 0; s < 2; ++s) {
            const int c = s * 4 + lo;
            const int slot = (c ^ sw) * 8;
            bf16x8 af[2], bfr[2];
            #pragma unroll
            for (int mt = 0; mt < 2; ++mt)
                af[mt] = *(const bf16x8*)(&As[mt * 16 + ln][slot]);
            #pragma unroll
            for (int nt = 0; nt < 2; ++nt)
                bfr[nt] = *(const bf16x8*)(&Bs[wave * 32 + nt * 16 + ln][slot]);
            #pragma unroll
            for (int mt = 0; mt < 2; ++mt)
                #pragma unroll
                for (int nt = 0; nt < 2; ++nt)
                    acc[mt][nt] = __builtin_amdgcn_mfma_f32_16x16x32_bf16(af[mt], bfr[nt], acc[mt][nt], 0, 0, 0);
        }
        __syncthreads();
    }
    #pragma unroll
    for (int mt = 0; mt < 2; ++mt)
        #pragma unroll
        for (int nt = 0; nt < 2; ++nt)
            #pragma unroll
            for (int r = 0; r < 4; ++r) {
                int m = m0 + mt * 16 + lo * 4 + r;
                int n = wave * 32 + nt * 16 + ln;
                float v = acc[mt][nt][r] + bias[n];
                Out[(size_t)m * NOUT + n] = 1.f / (1.f + __expf(-v));
            }
}

extern "C" void kernel_launch(void* const* d_in, const int* in_sizes, int n_in,
                              void* d_out, int out_size, void* d_ws, size_t ws_size,
                              hipStream_t stream)
{
    const float* x   = (const float*)d_in[0];
    const float* w1  = (const float*)d_in[1];
    const float* b1  = (const float*)d_in[2];
    const float* g1  = (const float*)d_in[3];
    const float* be1 = (const float*)d_in[4];
    const float* m1  = (const float*)d_in[5];
    const float* v1  = (const float*)d_in[6];
    const float* w2  = (const float*)d_in[7];
    const float* b2  = (const float*)d_in[8];
    const float* g2  = (const float*)d_in[9];
    const float* be2 = (const float*)d_in[10];
    const float* m2  = (const float*)d_in[11];
    const float* v2  = (const float*)d_in[12];
    const float* wa  = (const float*)d_in[13];
    const float* ba  = (const float*)d_in[14];
    const float* wd1 = (const float*)d_in[15];
    const float* bd1 = (const float*)d_in[16];
    const float* wd2 = (const float*)d_in[17];
    const float* bd2 = (const float*)d_in[18];

    char* ws = (char*)d_ws;
    const size_t SZ_F  = 67108864;          // f: 64 MiB
    const size_t SZ_H1 = 8388608;           // h1: 8 MiB

    __bf16* f_bf  = (__bf16*)ws;
    __bf16* h1_bf = (__bf16*)(ws + SZ_F);
    char*   tail  = ws + SZ_F + SZ_H1;
    __bf16* wd1_bf = (__bf16*)tail;                       // 4 MiB (permuted)
    __bf16* wd2_bf = (__bf16*)(tail + 4194304);           // 128 KiB
    __bf16* w2r_bf = (__bf16*)(tail + 4194304 + 131072);  // 64 KiB slot
    __bf16* w1r_bf = (__bf16*)(tail + 4194304 + 131072 + 65536); // 8 KiB

    // one merged prep dispatch: blocks 0-511 = wd1 permute, 512-855 = small prep
    prep_all_kernel<<<856, 256, 0, stream>>>(wd1, wd1_bf, wd2, w1, w2, wd2_bf, w1r_bf, w2r_bf);

    conv_fused_kernel<<<8192, 256, 0, stream>>>(x, w1r_bf, b1, g1, be1, m1, v1,
                                                w2r_bf, b2, g2, be2, m2, v2, wa, ba, f_bf);

    gemm1_ib_kernel<<<512, 512, 0, stream>>>(f_bf, wd1_bf, bd1, h1_bf);

    gemm2_kernel<<<256, 256, 0, stream>>>(h1_bf, wd2_bf, bd2, (float*)d_out);
}